// Round 26
// baseline (27.045 us; speedup 1.0000x reference)
//
#include <hip/hip_runtime.h>

#define BB 8
#define NN 256
#define DD 128
#define LN_EPS 1e-5f

// ---------------------------------------------------------------------------
// k_proj: hi = x @ w1[:D],  hjb = x @ w1[D:] + b1   (R25 verbatim)
// grid 512 blocks (4 rows) x 512 threads -> 2 blocks/CU.
// ---------------------------------------------------------------------------
__global__ __launch_bounds__(512, 2) void k_proj(const float* __restrict__ x,
                                                 const float* __restrict__ w1,
                                                 const float* __restrict__ b1,
                                                 float* __restrict__ hi,
                                                 float* __restrict__ hjb) {
    __shared__ float xs[4 * DD];       // 2 KB
    __shared__ float part[8192];       // 32 KB: A @0, B @4096
    const int bid  = blockIdx.x;
    const int row0 = (bid & 7) * NN + (bid >> 3) * 4;   // XCD-affine, 4 rows
    const int tid  = threadIdx.x;
    xs[tid] = x[row0 * DD + tid];      // 512 = 4*128 exactly
    __syncthreads();

    const int dp = tid & 127;
    const int kg = tid >> 7;     // 0..3
    const int kb = kg * 32;

    float aA[4] = {}, aB[4] = {};
    #pragma unroll
    for (int k4 = 0; k4 < 8; ++k4) {
        const int k0 = kb + k4 * 4;
        float wa[4], wb[4];
        #pragma unroll
        for (int q = 0; q < 4; ++q) {
            wa[q] = w1[(k0 + q) * DD + dp];
            wb[q] = w1[(DD + k0 + q) * DD + dp];
        }
        #pragma unroll
        for (int r = 0; r < 4; ++r) {
            const float4 xv = *(const float4*)&xs[r * DD + k0];  // broadcast
            aA[r] = fmaf(xv.x, wa[0], aA[r]);
            aA[r] = fmaf(xv.y, wa[1], aA[r]);
            aA[r] = fmaf(xv.z, wa[2], aA[r]);
            aA[r] = fmaf(xv.w, wa[3], aA[r]);
            aB[r] = fmaf(xv.x, wb[0], aB[r]);
            aB[r] = fmaf(xv.y, wb[1], aB[r]);
            aB[r] = fmaf(xv.z, wb[2], aB[r]);
            aB[r] = fmaf(xv.w, wb[3], aB[r]);
        }
    }
    #pragma unroll
    for (int r = 0; r < 4; ++r) {
        part[kg * 512 + r * DD + dp]        = aA[r];
        part[4096 + kg * 512 + r * DD + dp] = aB[r];
    }
    __syncthreads();
    {
        int r = tid >> 7, d = tid & 127;
        float sa = 0.f, sb = 0.f;
        #pragma unroll
        for (int w = 0; w < 4; ++w) {
            sa += part[w * 512 + r * DD + d];
            sb += part[4096 + w * 512 + r * DD + d];
        }
        hi [(row0 + r) * DD + d] = sa;
        hjb[(row0 + r) * DD + d] = sb + b1[d];
    }
}

// ---------------------------------------------------------------------------
// k_fused: R25 shell; pair phase at 2 rows x 4 d per thread with transposed
// a_tt[256][8] (1 float2 = 2 rows' a) -> pair LDS instrs 2048 -> 1024 per CU,
// single-phase partial commit (8 x [8][128] fits the hall alias), live pair
// state 16 regs (no spill at the 64-VGPR budget).
// Dynamic LDS (floats), total 37928 (~148 KB):
//   [0,32768)     hall[256][128]  (alias partP[8][1024]/partT[8][1024])
//   [32768,34816) a_tt[256][8]    (alias u1s@32768, resS@33792 in tail)
//   [34816,35840) xs | [35840,36864) ssp | [36864,37888) aggs
//   [37888,37920) asub[8][4] | [37920,37928) asum_s[8]
// ---------------------------------------------------------------------------
__global__ __launch_bounds__(1024, 4) void k_fused(const float* __restrict__ adj,
                                                   const float* __restrict__ x,
                                                   const float* __restrict__ hi,
                                                   const float* __restrict__ hjb,
                                                   const float* __restrict__ w2,
                                                   const float* __restrict__ b2,
                                                   const float* __restrict__ w3,
                                                   const float* __restrict__ b3,
                                                   const float* __restrict__ w4,
                                                   const float* __restrict__ b4,
                                                   const float* __restrict__ g,
                                                   const float* __restrict__ bet,
                                                   float* __restrict__ out) {
    extern __shared__ float smem[];
    float* const hall   = smem;            // [256][128]
    float* const partP  = smem;            // [8][1024] alias (pair done)
    float* const partT  = smem;            // [8][1024] alias
    float* const a_tt   = smem + 32768;    // [256][8]
    float* const u1s    = smem + 32768;    // [8][128] alias (a_tt dead)
    float* const resS   = smem + 33792;    // [8][128] alias
    float* const xs     = smem + 34816;    // [8][128]
    float* const ssp    = smem + 35840;    // [8][128]
    float* const aggs   = smem + 36864;    // [8][128]
    float* const asub   = smem + 37888;    // [8][4]
    float* const asum_s = smem + 37920;    // [8]

    const int bid = blockIdx.x;
    const int b   = bid & 7;               // XCD-affine batch
    const int i0  = (bid >> 3) * 8;
    const int tid = threadIdx.x;
    const int lane = tid & 63;

    // ---- stage FULL batch hjb (128 KB), transposed masked adjacency, x
    {
        const float4* src = (const float4*)(hjb + ((size_t)b * NN) * DD);
        float4* dst = (float4*)hall;
        #pragma unroll
        for (int t = 0; t < 8; ++t) dst[tid + t * 1024] = src[tid + t * 1024];
    }
    #pragma unroll
    for (int t = 0; t < 2; ++t) {
        int idx = tid + t * 1024;           // 0..2047
        int il = idx >> 8, j = idx & 255;   // il wave-uniform
        int ig = i0 + il;
        float av = adj[((size_t)b * NN + ig) * NN + j];
        av = (j == ig) ? 0.f : av;
        a_tt[j * 8 + il] = av;
        float s = av;
        #pragma unroll
        for (int m = 32; m; m >>= 1) s += __shfl_xor(s, m);
        if (lane == 0) asub[il * 4 + ((idx >> 6) & 3)] = s;
    }
    xs[tid] = x[((size_t)b * NN + i0) * DD + tid];
    __syncthreads();

    if (tid < 8)
        asum_s[tid] = asub[tid * 4] + asub[tid * 4 + 1]
                    + asub[tid * 4 + 2] + asub[tid * 4 + 3];

    // ---- pair: 2 rows x 4 d per thread, 8-way j-split, NO in-loop barriers
    const int dq = tid & 31;         // d-quad (d0 = dq*4)
    const int rg = (tid >> 5) & 3;   // rows rg*2, rg*2+1
    const int js = tid >> 7;         // 0..7 (j-split of 32)
    const float4 hi0 = *(const float4*)&hi[((size_t)b * NN + i0 + rg * 2) * DD + dq * 4];
    const float4 hi1 = *(const float4*)&hi[((size_t)b * NN + i0 + rg * 2 + 1) * DD + dq * 4];
    float4 acc0 = {0.f, 0.f, 0.f, 0.f}, acc1 = {0.f, 0.f, 0.f, 0.f};
    {
        const int j0 = js * 32;
        #pragma unroll 8
        for (int jj = 0; jj < 32; ++jj) {
            const int j = j0 + jj;
            const float4 hv = *(const float4*)&hall[j * 128 + dq * 4];
            const float2 a2 = *(const float2*)&a_tt[j * 8 + rg * 2];
            acc0.x = fmaf(fmaxf(hi0.x + hv.x, 0.f), a2.x, acc0.x);
            acc0.y = fmaf(fmaxf(hi0.y + hv.y, 0.f), a2.x, acc0.y);
            acc0.z = fmaf(fmaxf(hi0.z + hv.z, 0.f), a2.x, acc0.z);
            acc0.w = fmaf(fmaxf(hi0.w + hv.w, 0.f), a2.x, acc0.w);
            acc1.x = fmaf(fmaxf(hi1.x + hv.x, 0.f), a2.y, acc1.x);
            acc1.y = fmaf(fmaxf(hi1.y + hv.y, 0.f), a2.y, acc1.y);
            acc1.z = fmaf(fmaxf(hi1.z + hv.z, 0.f), a2.y, acc1.z);
            acc1.w = fmaf(fmaxf(hi1.w + hv.w, 0.f), a2.y, acc1.w);
        }
    }
    __syncthreads();       // all hall/a_tt reads done before partP alias writes
    {
        float* pp = partP + js * 1024 + (rg * 2) * 128 + dq * 4;
        *(float4*)(pp)       = acc0;
        *(float4*)(pp + 128) = acc1;
    }
    __syncthreads();
    {
        float s = 0.f;
        #pragma unroll
        for (int w = 0; w < 8; ++w) s += partP[w * 1024 + tid];
        ssp[tid] = s;
    }
    __syncthreads();

    // ---- tail: 1 col/thread (dp), 8-way k-split (kg), 16 k each (R25)
    const int dp = tid & 127;
    const int kg = tid >> 7;            // 0..7
    const int kb = kg * 16;

    // stage A: agg = ssp @ w2 (+ b2*asum at combine)
    {
        float w0[16];
        #pragma unroll
        for (int k = 0; k < 16; ++k) w0[k] = w2[(kb + k) * DD + dp];
        #pragma unroll
        for (int r = 0; r < 8; ++r) {
            float a0 = 0.f;
            #pragma unroll
            for (int q = 0; q < 4; ++q) {
                const float4 sv = *(const float4*)&ssp[r * 128 + kb + q * 4];
                a0 = fmaf(sv.x, w0[q*4+0], a0);
                a0 = fmaf(sv.y, w0[q*4+1], a0);
                a0 = fmaf(sv.z, w0[q*4+2], a0);
                a0 = fmaf(sv.w, w0[q*4+3], a0);
            }
            partT[kg * 1024 + r * 128 + dp] = a0;
        }
    }
    __syncthreads();
    {
        int r = tid >> 7, d = tid & 127;
        float s = 0.f;
        #pragma unroll
        for (int w = 0; w < 8; ++w) s += partT[w * 1024 + tid];
        aggs[tid] = s + b2[d] * asum_s[r];
    }
    __syncthreads();

    // stage B: u1 = relu(x@w3a + agg@w3b + b3)
    {
        float wa0[16], wb0[16];
        #pragma unroll
        for (int k = 0; k < 16; ++k) {
            wa0[k] = w3[(kb + k) * DD + dp];
            wb0[k] = w3[(DD + kb + k) * DD + dp];
        }
        #pragma unroll
        for (int r = 0; r < 8; ++r) {
            float a0 = 0.f;
            #pragma unroll
            for (int q = 0; q < 4; ++q) {
                const float4 xv = *(const float4*)&xs[r * 128 + kb + q * 4];
                const float4 av = *(const float4*)&aggs[r * 128 + kb + q * 4];
                a0 = fmaf(xv.x, wa0[q*4+0], a0);
                a0 = fmaf(xv.y, wa0[q*4+1], a0);
                a0 = fmaf(xv.z, wa0[q*4+2], a0);
                a0 = fmaf(xv.w, wa0[q*4+3], a0);
                a0 = fmaf(av.x, wb0[q*4+0], a0);
                a0 = fmaf(av.y, wb0[q*4+1], a0);
                a0 = fmaf(av.z, wb0[q*4+2], a0);
                a0 = fmaf(av.w, wb0[q*4+3], a0);
            }
            partT[kg * 1024 + r * 128 + dp] = a0;
        }
    }
    __syncthreads();
    {
        int d = tid & 127;
        float s = 0.f;
        #pragma unroll
        for (int w = 0; w < 8; ++w) s += partT[w * 1024 + tid];
        u1s[tid] = fmaxf(s + b3[d], 0.f);
    }
    __syncthreads();

    // stage C: upd = u1 @ w4; res = x + upd + b4
    {
        float w0[16];
        #pragma unroll
        for (int k = 0; k < 16; ++k) w0[k] = w4[(kb + k) * DD + dp];
        #pragma unroll
        for (int r = 0; r < 8; ++r) {
            float a0 = 0.f;
            #pragma unroll
            for (int q = 0; q < 4; ++q) {
                const float4 uv = *(const float4*)&u1s[r * 128 + kb + q * 4];
                a0 = fmaf(uv.x, w0[q*4+0], a0);
                a0 = fmaf(uv.y, w0[q*4+1], a0);
                a0 = fmaf(uv.z, w0[q*4+2], a0);
                a0 = fmaf(uv.w, w0[q*4+3], a0);
            }
            partT[kg * 1024 + r * 128 + dp] = a0;
        }
    }
    __syncthreads();
    {
        int d = tid & 127;
        float s = xs[tid] + b4[d];
        #pragma unroll
        for (int w = 0; w < 8; ++w) s += partT[w * 1024 + tid];
        resS[tid] = s;
    }
    __syncthreads();

    // ---- LayerNorm: waves 0..7, one row each, 2 d's per lane
    if (tid < 512) {
        const int r = tid >> 6, l = tid & 63;
        const float2 v = *(const float2*)&resS[r * 128 + l * 2];
        float s1 = v.x + v.y;
        float s2 = v.x * v.x + v.y * v.y;
        #pragma unroll
        for (int m = 32; m; m >>= 1) {
            s1 += __shfl_xor(s1, m);
            s2 += __shfl_xor(s2, m);
        }
        const float mu = s1 * (1.f / DD);
        const float rs = rsqrtf(s2 * (1.f / DD) - mu * mu + LN_EPS);
        const int d = l * 2;
        const float2 gv = *(const float2*)&g[d];
        const float2 bv = *(const float2*)&bet[d];
        float2 o;
        o.x = (v.x - mu) * rs * gv.x + bv.x;
        o.y = (v.y - mu) * rs * gv.y + bv.y;
        *(float2*)&out[((size_t)b * NN + i0 + r) * DD + d] = o;
    }
}

extern "C" void kernel_launch(void* const* d_in, const int* in_sizes, int n_in,
                              void* d_out, int out_size, void* d_ws, size_t ws_size,
                              hipStream_t stream) {
    (void)in_sizes; (void)n_in; (void)out_size; (void)ws_size;
    const float* x      = (const float*)d_in[0];
    const float* adj    = (const float*)d_in[1];
    const float* msg_w1 = (const float*)d_in[2];
    const float* msg_b1 = (const float*)d_in[3];
    const float* msg_w2 = (const float*)d_in[4];
    const float* msg_b2 = (const float*)d_in[5];
    const float* upd_w1 = (const float*)d_in[6];
    const float* upd_b1 = (const float*)d_in[7];
    const float* upd_w2 = (const float*)d_in[8];
    const float* upd_b2 = (const float*)d_in[9];
    const float* ln_g   = (const float*)d_in[10];
    const float* ln_b   = (const float*)d_in[11];
    float* out = (float*)d_out;

    const size_t BND = (size_t)BB * NN * DD;
    float* ws  = (float*)d_ws;
    float* hi  = ws;            // B*N*D
    float* hjb = ws + BND;      // B*N*D

    const size_t dyn_lds = 37928 * sizeof(float);   // ~148 KB (<= 160 KB/CU)
    hipFuncSetAttribute((const void*)k_fused,
                        hipFuncAttributeMaxDynamicSharedMemorySize,
                        (int)dyn_lds);

    k_proj<<<dim3(512), dim3(512), 0, stream>>>(x, msg_w1, msg_b1, hi, hjb);
    k_fused<<<dim3(256), dim3(1024), dyn_lds, stream>>>(adj, x, hi, hjb,
                                                        msg_w2, msg_b2,
                                                        upd_w1, upd_b1,
                                                        upd_w2, upd_b2,
                                                        ln_g, ln_b, out);
}

// Round 27
// 25.677 us; speedup vs baseline: 1.0533x; 1.0533x over previous
//
#include <hip/hip_runtime.h>

#define BB 8
#define NN 256
#define DD 128
#define LN_EPS 1e-5f

// ---------------------------------------------------------------------------
// k_proj: hi = x @ w1[:D],  hjb = x @ w1[D:] + b1
// grid 512 blocks (4 rows) x 512 threads -> 2 blocks/CU.
// XCD-affinity: batch = bid & 7.
// ---------------------------------------------------------------------------
__global__ __launch_bounds__(512, 2) void k_proj(const float* __restrict__ x,
                                                 const float* __restrict__ w1,
                                                 const float* __restrict__ b1,
                                                 float* __restrict__ hi,
                                                 float* __restrict__ hjb) {
    __shared__ float xs[4 * DD];       // 2 KB
    __shared__ float part[8192];       // 32 KB: A @0, B @4096
    const int bid  = blockIdx.x;
    const int row0 = (bid & 7) * NN + (bid >> 3) * 4;   // XCD-affine, 4 rows
    const int tid  = threadIdx.x;
    xs[tid] = x[row0 * DD + tid];      // 512 = 4*128 exactly
    __syncthreads();

    const int dp = tid & 127;
    const int kg = tid >> 7;     // 0..3
    const int kb = kg * 32;

    float aA[4] = {}, aB[4] = {};
    #pragma unroll
    for (int k4 = 0; k4 < 8; ++k4) {
        const int k0 = kb + k4 * 4;
        float wa[4], wb[4];
        #pragma unroll
        for (int q = 0; q < 4; ++q) {
            wa[q] = w1[(k0 + q) * DD + dp];
            wb[q] = w1[(DD + k0 + q) * DD + dp];
        }
        #pragma unroll
        for (int r = 0; r < 4; ++r) {
            const float4 xv = *(const float4*)&xs[r * DD + k0];  // broadcast
            aA[r] = fmaf(xv.x, wa[0], aA[r]);
            aA[r] = fmaf(xv.y, wa[1], aA[r]);
            aA[r] = fmaf(xv.z, wa[2], aA[r]);
            aA[r] = fmaf(xv.w, wa[3], aA[r]);
            aB[r] = fmaf(xv.x, wb[0], aB[r]);
            aB[r] = fmaf(xv.y, wb[1], aB[r]);
            aB[r] = fmaf(xv.z, wb[2], aB[r]);
            aB[r] = fmaf(xv.w, wb[3], aB[r]);
        }
    }
    #pragma unroll
    for (int r = 0; r < 4; ++r) {
        part[kg * 512 + r * DD + dp]        = aA[r];
        part[4096 + kg * 512 + r * DD + dp] = aB[r];
    }
    __syncthreads();
    {
        int r = tid >> 7, d = tid & 127;
        float sa = 0.f, sb = 0.f;
        #pragma unroll
        for (int w = 0; w < 4; ++w) {
            sa += part[w * 512 + r * DD + d];
            sb += part[4096 + w * 512 + r * DD + d];
        }
        hi [(row0 + r) * DD + d] = sa;
        hjb[(row0 + r) * DD + d] = sb + b1[d];
    }
}

// ---------------------------------------------------------------------------
// k_fused: champion (R24/R25). One-shot full-batch hjb stage into 128 KB
// dynamic LDS; zero in-loop barriers in the pair phase; 16 waves/CU.
// Dynamic LDS layout (floats), total 37896 (~148 KB -> 1 block/CU):
//   [0,32768)     hall[256][128]  (aliased by partP[4][1024]/partT[8][1024])
//   [32768,34816) a_t[8][256]     (aliased by u1s@32768, resS@33792 in tail)
//   [34816,35840) xs | [35840,36864) ssp | [36864,37888) aggs
//   [37888,37896) asum_s
// XCD-affine (b = bid & 7).
// ---------------------------------------------------------------------------
__global__ __launch_bounds__(1024, 4) void k_fused(const float* __restrict__ adj,
                                                   const float* __restrict__ x,
                                                   const float* __restrict__ hi,
                                                   const float* __restrict__ hjb,
                                                   const float* __restrict__ w2,
                                                   const float* __restrict__ b2,
                                                   const float* __restrict__ w3,
                                                   const float* __restrict__ b3,
                                                   const float* __restrict__ w4,
                                                   const float* __restrict__ b4,
                                                   const float* __restrict__ g,
                                                   const float* __restrict__ bet,
                                                   float* __restrict__ out) {
    extern __shared__ float smem[];
    float* const hall   = smem;            // [256][128]
    float* const partP  = smem;            // [4][1024] alias (pair done)
    float* const partT  = smem;            // [8][1024] alias
    float* const a_t    = smem + 32768;    // [8][256]
    float* const u1s    = smem + 32768;    // [8][128] alias (a_t dead)
    float* const resS   = smem + 33792;    // [8][128] alias
    float* const xs     = smem + 34816;    // [8][128]
    float* const ssp    = smem + 35840;    // [8][128]
    float* const aggs   = smem + 36864;    // [8][128]
    float* const asum_s = smem + 37888;    // [8]

    const int bid = blockIdx.x;
    const int b   = bid & 7;               // XCD-affine batch
    const int i0  = (bid >> 3) * 8;
    const int tid = threadIdx.x;

    // ---- stage FULL batch hjb (128 KB), masked adjacency, x rows
    {
        const float4* src = (const float4*)(hjb + ((size_t)b * NN) * DD);
        float4* dst = (float4*)hall;
        #pragma unroll
        for (int t = 0; t < 8; ++t) dst[tid + t * 1024] = src[tid + t * 1024];
    }
    #pragma unroll
    for (int t = 0; t < 2; ++t) {
        int idx = tid + t * 1024;           // 0..2047
        int il = idx >> 8, j = idx & 255;
        int ig = i0 + il;
        float av = adj[((size_t)b * NN + ig) * NN + j];
        a_t[il * 256 + j] = (j == ig) ? 0.f : av;
    }
    xs[tid] = x[((size_t)b * NN + i0) * DD + tid];
    __syncthreads();

    // ---- asum: waves 0..7, one row each
    if (tid < 512) {
        int r = tid >> 6, l = tid & 63;
        float s = a_t[r * 256 + l] + a_t[r * 256 + l + 64]
                + a_t[r * 256 + l + 128] + a_t[r * 256 + l + 192];
        #pragma unroll
        for (int m = 32; m; m >>= 1) s += __shfl_xor(s, m);
        if (l == 0) asum_s[r] = s;
    }

    // ---- pair: 64 j per thread, NO barriers in the loop
    const int dq  = tid & 31;        // d-quad
    const int row = (tid >> 5) & 7;
    const int jh  = tid >> 8;        // 0..3 (j-quarter)
    const float4 hi4 = *(const float4*)&hi[((size_t)b * NN + i0 + row) * DD + dq * 4];
    float4 acc = {0.f, 0.f, 0.f, 0.f};
    {
        const int j0 = jh * 64;
        #pragma unroll 8
        for (int jj = 0; jj < 64; ++jj) {
            const int j = j0 + jj;
            const float4 hv = *(const float4*)&hall[j * 128 + dq * 4];
            const float a = a_t[row * 256 + j];
            acc.x = fmaf(fmaxf(hi4.x + hv.x, 0.f), a, acc.x);
            acc.y = fmaf(fmaxf(hi4.y + hv.y, 0.f), a, acc.y);
            acc.z = fmaf(fmaxf(hi4.z + hv.z, 0.f), a, acc.z);
            acc.w = fmaf(fmaxf(hi4.w + hv.w, 0.f), a, acc.w);
        }
    }
    __syncthreads();       // all hall reads done before partP alias writes
    *(float4*)&partP[jh * 1024 + row * 128 + dq * 4] = acc;
    __syncthreads();
    {
        float s = partP[tid] + partP[1024 + tid] + partP[2048 + tid] + partP[3072 + tid];
        ssp[tid] = s;
    }
    __syncthreads();

    // ---- tail: 1 col/thread (dp), 8-way k-split (kg), 16 k each
    const int dp = tid & 127;
    const int kg = tid >> 7;            // 0..7
    const int kb = kg * 16;

    // stage A: agg = ssp @ w2 (+ b2*asum at combine)
    {
        float w0[16];
        #pragma unroll
        for (int k = 0; k < 16; ++k) w0[k] = w2[(kb + k) * DD + dp];
        #pragma unroll
        for (int r = 0; r < 8; ++r) {
            float a0 = 0.f;
            #pragma unroll
            for (int q = 0; q < 4; ++q) {
                const float4 sv = *(const float4*)&ssp[r * 128 + kb + q * 4];
                a0 = fmaf(sv.x, w0[q*4+0], a0);
                a0 = fmaf(sv.y, w0[q*4+1], a0);
                a0 = fmaf(sv.z, w0[q*4+2], a0);
                a0 = fmaf(sv.w, w0[q*4+3], a0);
            }
            partT[kg * 1024 + r * 128 + dp] = a0;
        }
    }
    __syncthreads();
    {
        int r = tid >> 7, d = tid & 127;
        float s = 0.f;
        #pragma unroll
        for (int w = 0; w < 8; ++w) s += partT[w * 1024 + tid];
        aggs[tid] = s + b2[d] * asum_s[r];
    }
    __syncthreads();

    // stage B: u1 = relu(x@w3a + agg@w3b + b3)
    {
        float wa0[16], wb0[16];
        #pragma unroll
        for (int k = 0; k < 16; ++k) {
            wa0[k] = w3[(kb + k) * DD + dp];
            wb0[k] = w3[(DD + kb + k) * DD + dp];
        }
        #pragma unroll
        for (int r = 0; r < 8; ++r) {
            float a0 = 0.f;
            #pragma unroll
            for (int q = 0; q < 4; ++q) {
                const float4 xv = *(const float4*)&xs[r * 128 + kb + q * 4];
                const float4 av = *(const float4*)&aggs[r * 128 + kb + q * 4];
                a0 = fmaf(xv.x, wa0[q*4+0], a0);
                a0 = fmaf(xv.y, wa0[q*4+1], a0);
                a0 = fmaf(xv.z, wa0[q*4+2], a0);
                a0 = fmaf(xv.w, wa0[q*4+3], a0);
                a0 = fmaf(av.x, wb0[q*4+0], a0);
                a0 = fmaf(av.y, wb0[q*4+1], a0);
                a0 = fmaf(av.z, wb0[q*4+2], a0);
                a0 = fmaf(av.w, wb0[q*4+3], a0);
            }
            partT[kg * 1024 + r * 128 + dp] = a0;
        }
    }
    __syncthreads();
    {
        int d = tid & 127;
        float s = 0.f;
        #pragma unroll
        for (int w = 0; w < 8; ++w) s += partT[w * 1024 + tid];
        u1s[tid] = fmaxf(s + b3[d], 0.f);
    }
    __syncthreads();

    // stage C: upd = u1 @ w4; res = x + upd + b4
    {
        float w0[16];
        #pragma unroll
        for (int k = 0; k < 16; ++k) w0[k] = w4[(kb + k) * DD + dp];
        #pragma unroll
        for (int r = 0; r < 8; ++r) {
            float a0 = 0.f;
            #pragma unroll
            for (int q = 0; q < 4; ++q) {
                const float4 uv = *(const float4*)&u1s[r * 128 + kb + q * 4];
                a0 = fmaf(uv.x, w0[q*4+0], a0);
                a0 = fmaf(uv.y, w0[q*4+1], a0);
                a0 = fmaf(uv.z, w0[q*4+2], a0);
                a0 = fmaf(uv.w, w0[q*4+3], a0);
            }
            partT[kg * 1024 + r * 128 + dp] = a0;
        }
    }
    __syncthreads();
    {
        int d = tid & 127;
        float s = xs[tid] + b4[d];
        #pragma unroll
        for (int w = 0; w < 8; ++w) s += partT[w * 1024 + tid];
        resS[tid] = s;
    }
    __syncthreads();

    // ---- LayerNorm: waves 0..7, one row each, 2 d's per lane
    if (tid < 512) {
        const int r = tid >> 6, l = tid & 63;
        const float2 v = *(const float2*)&resS[r * 128 + l * 2];
        float s1 = v.x + v.y;
        float s2 = v.x * v.x + v.y * v.y;
        #pragma unroll
        for (int m = 32; m; m >>= 1) {
            s1 += __shfl_xor(s1, m);
            s2 += __shfl_xor(s2, m);
        }
        const float mu = s1 * (1.f / DD);
        const float rs = rsqrtf(s2 * (1.f / DD) - mu * mu + LN_EPS);
        const int d = l * 2;
        const float2 gv = *(const float2*)&g[d];
        const float2 bv = *(const float2*)&bet[d];
        float2 o;
        o.x = (v.x - mu) * rs * gv.x + bv.x;
        o.y = (v.y - mu) * rs * gv.y + bv.y;
        *(float2*)&out[((size_t)b * NN + i0 + r) * DD + d] = o;
    }
}

extern "C" void kernel_launch(void* const* d_in, const int* in_sizes, int n_in,
                              void* d_out, int out_size, void* d_ws, size_t ws_size,
                              hipStream_t stream) {
    (void)in_sizes; (void)n_in; (void)out_size; (void)ws_size;
    const float* x      = (const float*)d_in[0];
    const float* adj    = (const float*)d_in[1];
    const float* msg_w1 = (const float*)d_in[2];
    const float* msg_b1 = (const float*)d_in[3];
    const float* msg_w2 = (const float*)d_in[4];
    const float* msg_b2 = (const float*)d_in[5];
    const float* upd_w1 = (const float*)d_in[6];
    const float* upd_b1 = (const float*)d_in[7];
    const float* upd_w2 = (const float*)d_in[8];
    const float* upd_b2 = (const float*)d_in[9];
    const float* ln_g   = (const float*)d_in[10];
    const float* ln_b   = (const float*)d_in[11];
    float* out = (float*)d_out;

    const size_t BND = (size_t)BB * NN * DD;
    float* ws  = (float*)d_ws;
    float* hi  = ws;            // B*N*D
    float* hjb = ws + BND;      // B*N*D

    const size_t dyn_lds = 37896 * sizeof(float);   // ~148 KB (<= 160 KB/CU)
    hipFuncSetAttribute((const void*)k_fused,
                        hipFuncAttributeMaxDynamicSharedMemorySize,
                        (int)dyn_lds);

    k_proj<<<dim3(512), dim3(512), 0, stream>>>(x, msg_w1, msg_b1, hi, hjb);
    k_fused<<<dim3(256), dim3(1024), dyn_lds, stream>>>(adj, x, hi, hjb,
                                                        msg_w2, msg_b2,
                                                        upd_w1, upd_b1,
                                                        upd_w2, upd_b2,
                                                        ln_g, ln_b, out);
}